// Round 5
// baseline (97.955 us; speedup 1.0000x reference)
//
#include <hip/hip_runtime.h>

// Problem dims (fixed by reference setup_inputs)
#define BDIM 256
#define IDIM 1024
#define ODIM 1024

#define NW 8                 // waves per block (i-split 8 x 128)
#define QLEN 128             // i per wave
#define NO 16                // outputs per block (runtime o-loop)
#define NPAIR (QLEN / 2)     // 64 v2f i-pairs per lane

typedef float v2f __attribute__((ext_vector_type(2)));

#if __has_builtin(__builtin_amdgcn_exp2f)
#define FAST_EXP2(v) __builtin_amdgcn_exp2f(v)
#else
#define FAST_EXP2(v) exp2f(v)
#endif

// ---------------------------------------------------------------------------
// Prep kernel: builds
//   wS[e][o][i'] = log2e * w[e*128 + i'][o]   (e = i-eighth; wave-linear layout)
//   xT[i][b]     = x[b][i]
// so the main kernel gets wave-uniform, linearly-consumed w (-> SMEM/SGPR)
// and coalesced one-time x loads.
// ---------------------------------------------------------------------------
__global__ __launch_bounds__(256)
void prep_kernel(const float* __restrict__ x, const float* __restrict__ w,
                 float* __restrict__ wS, float* __restrict__ xT) {
  __shared__ float lt[64][65];         // padded tile: conflict-free transpose
  const int tid = threadIdx.x;
  const float LOG2E = 1.4426950408889634f;
  const int t = blockIdx.x;
  if (t < 256) {
    // ---- w tiles: 16 (i) x 16 (o), 64x64 each ----
    const int i0 = (t >> 4) * 64, o0 = (t & 15) * 64;
#pragma unroll
    for (int k = 0; k < 16; ++k) {
      int idx = tid + k * 256, r = idx >> 6, c = idx & 63;   // r: i, c: o
      lt[r][c] = LOG2E * w[(size_t)(i0 + r) * ODIM + o0 + c];
    }
    __syncthreads();
#pragma unroll
    for (int k = 0; k < 16; ++k) {
      int idx = tid + k * 256, ol = idx >> 6, il = idx & 63;  // il fast: coalesced
      int gi = i0 + il, go = o0 + ol;
      int e = gi >> 7, ip = gi & 127;                         // 64-tile stays in one e
      wS[(size_t)e * (ODIM * QLEN) + (size_t)go * QLEN + ip] = lt[il][ol];
    }
  } else {
    // ---- x tiles: 16 (i) x 4 (b), 64x64 each ----
    const int t2 = t - 256;
    const int i0 = (t2 >> 2) * 64, b0 = (t2 & 3) * 64;
#pragma unroll
    for (int k = 0; k < 16; ++k) {
      int idx = tid + k * 256, r = idx >> 6, c = idx & 63;   // r: b, c: i
      lt[r][c] = x[(size_t)(b0 + r) * IDIM + i0 + c];
    }
    __syncthreads();
#pragma unroll
    for (int k = 0; k < 16; ++k) {
      int idx = tid + k * 256, il = idx >> 6, bl = idx & 63;  // bl fast: coalesced
      xT[(size_t)(i0 + il) * BDIM + b0 + bl] = lt[bl][il];
    }
  }
}

// ---------------------------------------------------------------------------
// Main kernel: lanes = batch rows. w is wave-uniform (SGPR via SMEM), x is
// loop-invariant in VGPRs. Inner loop = pure pk-VALU + v_exp, no VMEM/LDS.
// ---------------------------------------------------------------------------
__global__ __launch_bounds__(512, 2)
void stl_main(const float* __restrict__ xT, const float* __restrict__ wS,
              const float* __restrict__ bias, float* __restrict__ out) {
  __shared__ float ps[NW][64][2 * NO];   // 64 KB: per-wave (num,den) partials

  const int tx = threadIdx.x;            // 0..63 -> batch row (lane)
  const int ty = threadIdx.y;            // 0..7  -> i-eighth (one wave each)
  const int o0 = blockIdx.x * NO;
  const int b0 = blockIdx.y * 64;
  const int tyu = __builtin_amdgcn_readfirstlane(ty);  // provably uniform
  const int qbase = tyu * QLEN;

  // ---- One-time: this lane's x slice (128 f32) into registers, v2f-packed.
  //      xT[i][b]: lane-stride 4B -> coalesced dword loads. Static indices only.
  v2f xv[NPAIR];
#pragma unroll
  for (int u = 0; u < NPAIR; ++u) {
    xv[u].x = xT[(size_t)(qbase + 2 * u) * BDIM + b0 + tx];
    xv[u].y = xT[(size_t)(qbase + 2 * u + 1) * BDIM + b0 + tx];
  }

  // Wave-uniform w stream: consumption is perfectly linear in wS.
  const float* wrow = wS + (size_t)tyu * (ODIM * QLEN) + (size_t)o0 * QLEN;

  for (int o = 0; o < NO; ++o) {
    const float* wr = wrow + (size_t)o * QLEN;   // uniform address -> s_load
    v2f accn = {0.f, 0.f}, accd = {0.f, 0.f};
#pragma unroll
    for (int k = 0; k < NPAIR; ++k) {
      v2f sw;
      sw.x = wr[2 * k];                          // SGPR pair operand
      sw.y = wr[2 * k + 1];
      v2f p = xv[k] * sw;                        // v_pk_mul (p = log2e*z)
      v2f t;
      t.x = FAST_EXP2(__builtin_fabsf(p.x));     // v_exp_f32 with abs folded
      t.y = FAST_EXP2(__builtin_fabsf(p.y));
      accn += p * t;                             // v_pk_fma
      accd += t;                                 // v_pk_add
    }
    v2f res;
    res.x = accn.x + accn.y;                     // num partial
    res.y = accd.x + accd.y;                     // den partial
    *(v2f*)&ps[ty][tx][2 * o] = res;             // ds_write_b64 (runtime o OK)
  }
  __syncthreads();

  // ---- Combine across the 8 i-waves: 512 threads x 2 outputs each ----
  const int tid = ty * 64 + tx;
  const int b = tid >> 3;                        // 0..63
  const int op = (tid & 7) * 2;                  // 0,2,...,14
  float n0 = 0.f, d0 = 0.f, n1 = 0.f, d1 = 0.f;
#pragma unroll
  for (int wv = 0; wv < NW; ++wv) {
    float4 a = *(const float4*)&ps[wv][b][2 * op];  // (n_o,d_o,n_o1,d_o1)
    n0 += a.x; d0 += a.y; n1 += a.z; d1 += a.w;
  }
  const float LN2 = 0.6931471805599453f;
  const float scale = (float)IDIM * LN2;         // undo log2e, apply n=IDIM
  float2 r;
  r.x = scale * n0 / d0 + bias[o0 + op];
  r.y = scale * n1 / d1 + bias[o0 + op + 1];
  *(float2*)&out[(size_t)(b0 + b) * ODIM + o0 + op] = r;
}

// ---------------------------------------------------------------------------
// Fallback (proven 41 us/dispatch) if workspace is too small for wS+xT.
// ---------------------------------------------------------------------------
#define TILE_OL 2
#define TILE_O (64 * TILE_OL)
#define TILE_B 4
#define FQLEN (IDIM / NW)
#define CHUNK 8
#define NCHUNK (FQLEN / CHUNK)

typedef float v4f __attribute__((ext_vector_type(4)));

__global__ __launch_bounds__(512, 4)
void stl_old(const float* __restrict__ x, const float* __restrict__ w,
             const float* __restrict__ bias, float* __restrict__ out) {
  __shared__ float xs[TILE_B][IDIM];
  __shared__ float ps[NW][64][16];

  const int tx = threadIdx.x, ty = threadIdx.y;
  const int tid = ty * 64 + tx;
  const int o0 = blockIdx.x * TILE_O;
  const int b0 = blockIdx.y * TILE_B;
  const float LOG2E = 1.4426950408889634f;

#pragma unroll
  for (int k = 0; k < 2; ++k) {
    int f = tid + k * 512, row = f >> 8, col = f & 255;
    float4 v = ((const float4*)(x + (size_t)(b0 + row) * IDIM))[col];
    v.x *= LOG2E; v.y *= LOG2E; v.z *= LOG2E; v.w *= LOG2E;
    ((float4*)(&xs[row][0]))[col] = v;
  }
  __syncthreads();

  const int qbase = ty * FQLEN;
  const float* wp = w + (size_t)qbase * ODIM + o0 + tx;

  v2f an[TILE_OL][TILE_B], ad[TILE_OL][TILE_B];
#pragma unroll
  for (int s = 0; s < TILE_OL; ++s)
#pragma unroll
    for (int r = 0; r < TILE_B; ++r) { an[s][r] = (v2f){0.f, 0.f}; ad[s][r] = (v2f){0.f, 0.f}; }

  v2f wA0[CHUNK / 2], wA1[CHUNK / 2], wB0[CHUNK / 2], wB1[CHUNK / 2];

#define WLOADF(d0_, d1_, cc)                                              \
  {                                                                       \
    const float* wq = wp + (size_t)((cc) * CHUNK) * ODIM;                 \
    _Pragma("unroll")                                                     \
    for (int u = 0; u < CHUNK / 2; ++u) {                                 \
      d0_[u].x = wq[(size_t)(2 * u) * ODIM];                              \
      d0_[u].y = wq[(size_t)(2 * u + 1) * ODIM];                          \
      d1_[u].x = wq[(size_t)(2 * u) * ODIM + 64];                         \
      d1_[u].y = wq[(size_t)(2 * u + 1) * ODIM + 64];                     \
    }                                                                     \
  }

#define ROWPF(acc_n, acc_d, xpair, wpair)                                 \
  {                                                                       \
    v2f p = (xpair) * (wpair);                                            \
    v2f t;                                                                \
    t.x = FAST_EXP2(__builtin_fabsf(p.x));                                \
    t.y = FAST_EXP2(__builtin_fabsf(p.y));                                \
    acc_n += p * t;                                                       \
    acc_d += t;                                                           \
  }

#define LOF(xq) __builtin_shufflevector(xq, xq, 0, 1)
#define HIF(xq) __builtin_shufflevector(xq, xq, 2, 3)

#define COMPUTEF(wc0, wc1, cc)                                            \
  {                                                                       \
    const int jb = qbase + (cc) * CHUNK;                                  \
    _Pragma("unroll")                                                     \
    for (int h = 0; h < 2; ++h) {                                         \
      v4f xq[TILE_B];                                                     \
      _Pragma("unroll")                                                   \
      for (int r = 0; r < TILE_B; ++r)                                    \
        xq[r] = *(const v4f*)(&xs[r][jb + h * 4]);                        \
      _Pragma("unroll")                                                   \
      for (int r = 0; r < TILE_B; ++r) {                                  \
        ROWPF(an[0][r], ad[0][r], LOF(xq[r]), wc0[h * 2])                 \
        ROWPF(an[0][r], ad[0][r], HIF(xq[r]), wc0[h * 2 + 1])             \
        ROWPF(an[1][r], ad[1][r], LOF(xq[r]), wc1[h * 2])                 \
        ROWPF(an[1][r], ad[1][r], HIF(xq[r]), wc1[h * 2 + 1])             \
      }                                                                   \
    }                                                                     \
  }

  WLOADF(wA0, wA1, 0)
  for (int c = 0; c < NCHUNK; c += 2) {
    WLOADF(wB0, wB1, c + 1)
    COMPUTEF(wA0, wA1, c)
    WLOADF(wA0, wA1, (c + 2) & (NCHUNK - 1))
    COMPUTEF(wB0, wB1, c + 1)
  }

#pragma unroll
  for (int s = 0; s < TILE_OL; ++s) {
    *(float4*)(&ps[ty][tx][s * 8 + 0]) =
        make_float4(an[s][0].x + an[s][0].y, an[s][1].x + an[s][1].y,
                    an[s][2].x + an[s][2].y, an[s][3].x + an[s][3].y);
    *(float4*)(&ps[ty][tx][s * 8 + 4]) =
        make_float4(ad[s][0].x + ad[s][0].y, ad[s][1].x + ad[s][1].y,
                    ad[s][2].x + ad[s][2].y, ad[s][3].x + ad[s][3].y);
  }
  __syncthreads();

  if (ty == 0) {
    const float LN2 = 0.6931471805599453f;
    const float scale = (float)IDIM * LN2;
#pragma unroll
    for (int s = 0; s < TILE_OL; ++s) {
      float n[4] = {0, 0, 0, 0}, d[4] = {0, 0, 0, 0};
#pragma unroll
      for (int q = 0; q < NW; ++q) {
        float4 a = *(const float4*)(&ps[q][tx][s * 8 + 0]);
        float4 b2 = *(const float4*)(&ps[q][tx][s * 8 + 4]);
        n[0] += a.x; n[1] += a.y; n[2] += a.z; n[3] += a.w;
        d[0] += b2.x; d[1] += b2.y; d[2] += b2.z; d[3] += b2.w;
      }
      const int o = o0 + tx + s * 64;
      const float bo = bias[o];
#pragma unroll
      for (int r = 0; r < 4; ++r)
        out[(size_t)(b0 + r) * ODIM + o] = scale * n[r] / d[r] + bo;
    }
  }
}

extern "C" void kernel_launch(void* const* d_in, const int* in_sizes, int n_in,
                              void* d_out, int out_size, void* d_ws, size_t ws_size,
                              hipStream_t stream) {
  const float* x = (const float*)d_in[0];    // [256,1024] f32
  const float* w = (const float*)d_in[1];    // [1024,1024] f32
  const float* b = (const float*)d_in[2];    // [1024] f32
  float* out = (float*)d_out;                // [256,1024] f32

  const size_t wS_bytes = (size_t)NW * ODIM * QLEN * sizeof(float);  // 4 MB
  const size_t xT_bytes = (size_t)IDIM * BDIM * sizeof(float);       // 1 MB

  if (ws_size >= wS_bytes + xT_bytes) {
    float* wS = (float*)d_ws;
    float* xT = (float*)((char*)d_ws + wS_bytes);
    prep_kernel<<<320, 256, 0, stream>>>(x, w, wS, xT);
    dim3 grid(ODIM / NO, BDIM / 64);        // (64, 4) = 256 blocks = 1/CU
    dim3 block(64, NW);                     // 512 threads = 8 waves
    stl_main<<<grid, block, 0, stream>>>(xT, wS, b, out);
  } else {
    dim3 grid(ODIM / TILE_O, BDIM / TILE_B);
    dim3 block(64, NW);
    stl_old<<<grid, block, 0, stream>>>(x, w, b, out);
  }
}